// Round 9
// baseline (357.367 us; speedup 1.0000x reference)
//
#include <hip/hip_runtime.h>
#include <hip/hip_bf16.h>

// dims: Bk=16, n=256, E=768, G=128, Cout_g=256, Cin_g=192, B=4, K=4, L=16, H=16, D=64
// out = [pooled 16*768][batch 131072*Tmax][valid 4*Tmax]
// ws (int32): [0..15] len per bseq, [16..31] cum, [32..35] total per b
// decode: g = ls*4 + beta (ls=l*2+s), d = beta*16 + (o>>4), h = o&15

typedef float f32x4 __attribute__((ext_vector_type(4)));
typedef __bf16 bf16x8 __attribute__((ext_vector_type(8)));
typedef unsigned short u16x4 __attribute__((ext_vector_type(4)));
typedef unsigned short u16x8 __attribute__((ext_vector_type(8)));

__device__ __forceinline__ unsigned short f2bf(float f) {
    union { float f; unsigned u; } v; v.f = f;
    unsigned r = v.u + 0x7FFFu + ((v.u >> 16) & 1u);
    return (unsigned short)(r >> 16);
}

__device__ __forceinline__ bf16x8 ldfrag(const unsigned short* p) {
    u16x8 r = *(const u16x8*)p;
    return __builtin_bit_cast(bf16x8, r);
}

// lens + prefix sums + valid flags
__global__ void cums_kernel(const int* __restrict__ mask, int* __restrict__ ws,
                            float* __restrict__ valid_out, int Tmax) {
    int tid = threadIdx.x;
    int w = tid >> 6, lane = tid & 63;
    int m = mask[w * 256 + lane] + mask[w * 256 + lane + 64] +
            mask[w * 256 + lane + 128] + mask[w * 256 + lane + 192];
#pragma unroll
    for (int off = 32; off > 0; off >>= 1) m += __shfl_down(m, off);
    if (lane == 0) ws[w] = m;
    __syncthreads();
    if (tid == 0) {
        for (int b = 0; b < 4; ++b) {
            int c = 0;
            for (int j = 0; j < 4; ++j) { ws[16 + b * 4 + j] = c; c += ws[b * 4 + j]; }
            ws[32 + b] = c;
        }
    }
    __syncthreads();
    for (int i = tid; i < 4 * Tmax; i += 1024) {
        int b = i / Tmax;
        int T = i - b * Tmax;
        valid_out[i] = (T < ws[32 + b]) ? 1.0f : 0.0f;
    }
}

// pooled: block = (bs, e-chunk of 64), 256 threads = 4 t-groups x 64 e
__global__ void pooled_kernel(const float* __restrict__ lh, const int* __restrict__ mask,
                              const int* __restrict__ ws, float* __restrict__ pooled) {
    int bs = blockIdx.x / 12;
    int ec = blockIdx.x - bs * 12;
    int tid = threadIdx.x;
    int tg = tid >> 6, lane = tid & 63;
    int e = ec * 64 + lane;
    float s = 0.f;
    for (int t = tg; t < 256; t += 4) {
        float mf = (float)mask[bs * 256 + t];
        s += lh[(size_t)(bs * 256 + t) * 768 + e] * mf;
    }
    __shared__ float red[4][64];
    red[tg][lane] = s;
    __syncthreads();
    if (tg == 0) {
        float tot = red[0][lane] + red[1][lane] + red[2][lane] + red[3][lane];
        pooled[bs * 768 + e] = tot / (float)ws[bs];
    }
}

// zero tail, row-contiguous: block = one (b,l,s,h) row, zeros [total[b], Tmax) x 64 d
__global__ void zerotail_kernel(float* __restrict__ batch, const int* __restrict__ ws,
                                int Tmax) {
    int rr = blockIdx.x;              // 0..2047
    int b = rr >> 9;
    int rem = rr & 511;               // l*32 + s*16 + h
    int l = rem >> 5, s = (rem >> 4) & 1, h = rem & 15;
    int total = ws[32 + b];
    int span = Tmax - total;
    if (span <= 0) return;
    float* row = batch + (((size_t)((l * 2 + s) * 4 + b) * 16 + h) * (size_t)Tmax + total) * 64;
    f32x4 z = {0.f, 0.f, 0.f, 0.f};
    int nchunk = span << 4;           // span*64 floats / 4
    for (int j = threadIdx.x; j < nchunk; j += 256)
        *(f32x4*)(row + (j << 2)) = z;
}

// All-beta GEMM, LDS-transpose epilogue with 1KB-burst stores, sized for 2 blocks/CU.
// block = (ls, bs, tq): M'=1024 (4 beta x 256 o) x N=32 t, K=192.
// 512 threads = 8 waves = (beta 0..3) x (oh 0..1); wave = 128 o x 32 t, acc[8][2] (64 VGPR).
// A: LDS bf16 [1024][32], chunk XOR-swizzled (2-way, free). B: global->reg.
// Epilogue: Ltr f32[128][68] transpose; 4 phases; store instr = 4t x 64d = 1KB contiguous.
__global__ __launch_bounds__(512, 4) void gemm_kernel(
    const float* __restrict__ lh, const float* __restrict__ wgt,
    const float* __restrict__ bias, const int* __restrict__ ws,
    float* __restrict__ out, int Tmax) {
    __shared__ __align__(16) unsigned short As[1024][32];   // 64KB; reused as Ltr f32[128][68]
    __shared__ __align__(16) float biasT[16][68];

    int x = blockIdx.x;
    int xcd = x & 7;
    int rest = x >> 3;              // 0..511
    int lsq = rest >> 7;            // 0..3
    int rb = rest & 127;
    int ls = (lsq << 3) + xcd;      // pinned per XCD; 128 consecutive bids share one A panel
    int bs = rb >> 3;
    int tq = rb & 7;

    int len = ws[bs];
    int tbase = tq << 5;
    if (tbase >= len) return;       // block-uniform

    int tid = threadIdx.x;

    // bias -> biasT[h][beta*16+dmid]
    {
        int i0 = tid, i1 = tid + 512;
        biasT[i0 & 15][((i0 >> 8) << 4) + ((i0 & 255) >> 4)] = bias[(ls << 10) + i0];
        biasT[i1 & 15][((i1 >> 8) << 4) + ((i1 & 255) >> 4)] = bias[(ls << 10) + i1];
    }

    int lane = tid & 63;
    int wv = tid >> 6;
    int beta = wv >> 1, oh = wv & 1;
    int p = lane & 15, q = lane >> 4;

    const float* Awg = wgt + (size_t)ls * 196608;   // [1024 o'][192 k] f32
    const float* Brow = lh + (size_t)bs * 196608 + (size_t)(tbase + p) * 768 +
                        beta * 192 + (q << 3);

    int arow0 = tid >> 2;           // 0..127
    int achk = tid & 3;             // 8-float chunk within the 32-k slab

    f32x4 acc[8][2] = {};
    f32x4 pf[2][2];

    // prologue: prefetch chunk 0, rows 0..255
#pragma unroll
    for (int it = 0; it < 2; ++it) {
        const float* src = Awg + (arow0 + (it << 7)) * 192 + (achk << 3);
        pf[it][0] = *(const f32x4*)src;
        pf[it][1] = *(const f32x4*)(src + 4);
    }

#pragma unroll
    for (int cc = 0; cc < 6; ++cc) {
        const int kk = cc << 5;
        // stage rows 0..255 from prefetch regs
#pragma unroll
        for (int it = 0; it < 2; ++it) {
            int row = arow0 + (it << 7);
            u16x8 aw = { f2bf(pf[it][0][0]), f2bf(pf[it][0][1]), f2bf(pf[it][0][2]), f2bf(pf[it][0][3]),
                         f2bf(pf[it][1][0]), f2bf(pf[it][1][1]), f2bf(pf[it][1][2]), f2bf(pf[it][1][3]) };
            *(u16x8*)&As[row][(achk ^ ((row >> 1) & 3)) << 3] = aw;
        }
        // stage rows 256..1023 direct
#pragma unroll
        for (int it = 2; it < 8; ++it) {
            int row = arow0 + (it << 7);
            const float* src = Awg + row * 192 + kk + (achk << 3);
            f32x4 a0 = *(const f32x4*)src;
            f32x4 a1 = *(const f32x4*)(src + 4);
            u16x8 aw = { f2bf(a0[0]), f2bf(a0[1]), f2bf(a0[2]), f2bf(a0[3]),
                         f2bf(a1[0]), f2bf(a1[1]), f2bf(a1[2]), f2bf(a1[3]) };
            *(u16x8*)&As[row][(achk ^ ((row >> 1) & 3)) << 3] = aw;
        }
        __syncthreads();
        // prefetch NEXT chunk rows 0..255 (in flight across MFMA)
        if (cc < 5) {
#pragma unroll
            for (int it = 0; it < 2; ++it) {
                const float* src = Awg + (arow0 + (it << 7)) * 192 + kk + 32 + (achk << 3);
                pf[it][0] = *(const f32x4*)src;
                pf[it][1] = *(const f32x4*)(src + 4);
            }
        }
        // B: global->reg, 2 t-fragments
        bf16x8 bf[2];
#pragma unroll
        for (int n = 0; n < 2; ++n) {
            const float* bp = Brow + n * 16 * 768 + kk;
            f32x4 b0 = *(const f32x4*)bp;
            f32x4 b1 = *(const f32x4*)(bp + 4);
            u16x8 bw = { f2bf(b0[0]), f2bf(b0[1]), f2bf(b0[2]), f2bf(b0[3]),
                         f2bf(b1[0]), f2bf(b1[1]), f2bf(b1[2]), f2bf(b1[3]) };
            bf[n] = __builtin_bit_cast(bf16x8, bw);
        }
        // MFMA: 8 o-subtiles x 2 t-fragments
#pragma unroll
        for (int r8 = 0; r8 < 8; ++r8) {
            int row = (beta << 8) + (oh << 7) + (r8 << 4) + p;
            bf16x8 af = ldfrag(&As[row][(q ^ ((row >> 1) & 3)) << 3]);
            acc[r8][0] = __builtin_amdgcn_mfma_f32_16x16x32_bf16(af, bf[0], acc[r8][0], 0, 0, 0);
            acc[r8][1] = __builtin_amdgcn_mfma_f32_16x16x32_bf16(af, bf[1], acc[r8][1], 0, 0, 0);
        }
        __syncthreads();
    }

    // ---- epilogue: transpose via Ltr f32[128][68], then 1KB-burst stores ----
    // lane (p,q) of wave (beta,oh) holds o = oh*128 + r8*16 + q*4 + r, t = tbase + n*16 + p
    // => d = beta*16 + oh*8 + r8, h = q*4 + r.
    float* Ltr = (float*)&As[0][0];
    int cum = ws[16 + bs];
    int b = bs >> 2;
    float* batch = out + 12288;
    size_t hd0 = (size_t)((ls << 2) + b) << 4;

    int toff = lane & 3, dcq = lane >> 2;
    int col0 = (beta << 4) + (oh << 3);

#pragma unroll
    for (int r = 0; r < 4; ++r) {
        // write phase: Ltr[row = tloc*4 + q][col0 .. col0+8)
#pragma unroll
        for (int n = 0; n < 2; ++n) {
            int rowL = (((n << 4) + p) << 2) + q;
            f32x4 v0 = { acc[0][n][r], acc[1][n][r], acc[2][n][r], acc[3][n][r] };
            f32x4 v1 = { acc[4][n][r], acc[5][n][r], acc[6][n][r], acc[7][n][r] };
            *(f32x4*)(Ltr + rowL * 68 + col0) = v0;
            *(f32x4*)(Ltr + rowL * 68 + col0 + 4) = v1;
        }
        __syncthreads();
        // burst-store phase: wave instr = 4 t x 64 d = 1KB contiguous
#pragma unroll
        for (int gi = 0; gi < 4; ++gi) {
            int flat = (wv << 2) + gi;      // 0..31
            int hq = flat >> 3, t4 = flat & 7;
            int tloc = (t4 << 2) + toff;
            int h = (hq << 2) + r;
            int tglob = tbase + tloc;
            f32x4 v = *(const f32x4*)(Ltr + ((tloc << 2) + hq) * 68 + (dcq << 2));
            v += *(const f32x4*)&biasT[h][dcq << 2];
            if (tglob < len) {
                float* dst = batch + ((hd0 + h) * (size_t)Tmax + cum + tglob) * 64;
                *(f32x4*)(dst + (dcq << 2)) = v;
            }
        }
        __syncthreads();
    }
}

extern "C" void kernel_launch(void* const* d_in, const int* in_sizes, int n_in,
                              void* d_out, int out_size, void* d_ws, size_t ws_size,
                              hipStream_t stream) {
    const float* lh   = (const float*)d_in[0];
    const int*   mask = (const int*)d_in[1];
    const float* wgt  = (const float*)d_in[2];
    const float* bias = (const float*)d_in[3];
    float* out = (float*)d_out;
    int* ws = (int*)d_ws;

    int Tmax = (out_size - 12288) / 131076;

    cums_kernel<<<1, 1024, 0, stream>>>(mask, ws, out + 12288 + (size_t)131072 * Tmax, Tmax);
    pooled_kernel<<<16 * 12, 256, 0, stream>>>(lh, mask, ws, out);
    zerotail_kernel<<<2048, 256, 0, stream>>>(out + 12288, ws, Tmax);
    gemm_kernel<<<4096, 512, 0, stream>>>(lh, wgt, bias, ws, out, Tmax);
}

// Round 10
// 228.898 us; speedup vs baseline: 1.5613x; 1.5613x over previous
//
#include <hip/hip_runtime.h>
#include <hip/hip_bf16.h>

// dims: Bk=16, n=256, E=768, G=128, Cout_g=256, Cin_g=192, B=4, K=4, L=16, H=16, D=64
// out = [pooled 16*768][batch 131072*Tmax][valid 4*Tmax]
// ws layout: int ctrl[64] @0 ([0..15] len, [16..31] cum, [32..35] total);
//            Wp u16 @byte 1024  (32 ls x 6 kk x 4096 slots x 8 = 12.58 MB, swizzle-baked)
//            Lp u16 @byte 1024+12582912 (16x256x768 bf16 = 6.29 MB)
// decode: g = ls*4 + beta, d = beta*16 + (o>>4), h = o&15

typedef float f32x4 __attribute__((ext_vector_type(4)));
typedef __bf16 bf16x8 __attribute__((ext_vector_type(8)));
typedef unsigned short u16x4 __attribute__((ext_vector_type(4)));
typedef unsigned short u16x8 __attribute__((ext_vector_type(8)));

__device__ __forceinline__ unsigned short f2bf(float f) {
    union { float f; unsigned u; } v; v.f = f;
    unsigned r = v.u + 0x7FFFu + ((v.u >> 16) & 1u);
    return (unsigned short)(r >> 16);
}

__device__ __forceinline__ bf16x8 ldfrag(const unsigned short* p) {
    u16x8 r = *(const u16x8*)p;
    return __builtin_bit_cast(bf16x8, r);
}

// lens + prefix sums + valid flags
__global__ void cums_kernel(const int* __restrict__ mask, int* __restrict__ ws,
                            float* __restrict__ valid_out, int Tmax) {
    int tid = threadIdx.x;
    int w = tid >> 6, lane = tid & 63;
    int m = mask[w * 256 + lane] + mask[w * 256 + lane + 64] +
            mask[w * 256 + lane + 128] + mask[w * 256 + lane + 192];
#pragma unroll
    for (int off = 32; off > 0; off >>= 1) m += __shfl_down(m, off);
    if (lane == 0) ws[w] = m;
    __syncthreads();
    if (tid == 0) {
        for (int b = 0; b < 4; ++b) {
            int c = 0;
            for (int j = 0; j < 4; ++j) { ws[16 + b * 4 + j] = c; c += ws[b * 4 + j]; }
            ws[32 + b] = c;
        }
    }
    __syncthreads();
    for (int i = tid; i < 4 * Tmax; i += 1024) {
        int b = i / Tmax;
        int T = i - b * Tmax;
        valid_out[i] = (T < ws[32 + b]) ? 1.0f : 0.0f;
    }
}

// pooled: block = (bs, e-chunk of 64), 256 threads = 4 t-groups x 64 e
__global__ void pooled_kernel(const float* __restrict__ lh, const int* __restrict__ mask,
                              const int* __restrict__ ws, float* __restrict__ pooled) {
    int bs = blockIdx.x / 12;
    int ec = blockIdx.x - bs * 12;
    int tid = threadIdx.x;
    int tg = tid >> 6, lane = tid & 63;
    int e = ec * 64 + lane;
    float s = 0.f;
    for (int t = tg; t < 256; t += 4) {
        float mf = (float)mask[bs * 256 + t];
        s += lh[(size_t)(bs * 256 + t) * 768 + e] * mf;
    }
    __shared__ float red[4][64];
    red[tg][lane] = s;
    __syncthreads();
    if (tg == 0) {
        float tot = red[0][lane] + red[1][lane] + red[2][lane] + red[3][lane];
        pooled[bs * 768 + e] = tot / (float)ws[bs];
    }
}

// zero tail, row-contiguous: block = one (b,l,s,h) row, zeros [total[b], Tmax) x 64 d
__global__ void zerotail_kernel(float* __restrict__ batch, const int* __restrict__ ws,
                                int Tmax) {
    int rr = blockIdx.x;              // 0..2047
    int b = rr >> 9;
    int rem = rr & 511;
    int l = rem >> 5, s = (rem >> 4) & 1, h = rem & 15;
    int total = ws[32 + b];
    int span = Tmax - total;
    if (span <= 0) return;
    float* row = batch + (((size_t)((l * 2 + s) * 4 + b) * 16 + h) * (size_t)Tmax + total) * 64;
    f32x4 z = {0.f, 0.f, 0.f, 0.f};
    int nchunk = span << 4;
    for (int j = threadIdx.x; j < nchunk; j += 256)
        *(f32x4*)(row + (j << 2)) = z;
}

// pack wgt f32 -> bf16 in LDS-linear order with XOR-swizzle baked in.
// slot s of (ls,kk): row = s>>2, sc = s&3; holds W[row][kk*32 + ((sc^((row>>1)&3))<<3) .. +8)
__global__ void packw_kernel(const float* __restrict__ wgt, unsigned short* __restrict__ Wp) {
    int bid = blockIdx.x;            // 0..3071
    int ls = bid / 96;
    int rem = bid - ls * 96;
    int kk = rem >> 4;
    int blk = rem & 15;
    int slot = (blk << 8) + threadIdx.x;
    int row = slot >> 2;
    int sc = slot & 3;
    int coloff = (sc ^ ((row >> 1) & 3)) << 3;
    const float* src = wgt + (size_t)ls * 196608 + row * 192 + (kk << 5) + coloff;
    f32x4 a0 = *(const f32x4*)src;
    f32x4 a1 = *(const f32x4*)(src + 4);
    u16x8 w = { f2bf(a0[0]), f2bf(a0[1]), f2bf(a0[2]), f2bf(a0[3]),
                f2bf(a1[0]), f2bf(a1[1]), f2bf(a1[2]), f2bf(a1[3]) };
    *(u16x8*)(Wp + (((size_t)(ls * 6 + kk) << 12) + slot) * 8) = w;
}

// pack lh f32 -> bf16 flat
__global__ void packlh_kernel(const float* __restrict__ lh, unsigned short* __restrict__ Lp) {
    size_t slot = (size_t)blockIdx.x * 256 + threadIdx.x;   // < 393216
    const float* src = lh + slot * 8;
    f32x4 a0 = *(const f32x4*)src;
    f32x4 a1 = *(const f32x4*)(src + 4);
    u16x8 w = { f2bf(a0[0]), f2bf(a0[1]), f2bf(a0[2]), f2bf(a0[3]),
                f2bf(a1[0]), f2bf(a1[1]), f2bf(a1[2]), f2bf(a1[3]) };
    *(u16x8*)(Lp + slot * 8) = w;
}

// All-beta GEMM; A via global_load_lds from pre-packed bf16 (PACKED) or f32+f2bf fallback.
// block = (ls, bs, tq): M'=1024 x N=32 t, K=192. 512 thr = 8 waves = (beta x oh).
// Epilogue: Ltr transpose + 1KB-burst stores (R9, correctness-proven).
template<bool PACKED>
__global__ __launch_bounds__(512, 4) void gemm_kernel(
    const float* __restrict__ lh, const float* __restrict__ wgt,
    const unsigned short* __restrict__ Wp, const unsigned short* __restrict__ Lp,
    const float* __restrict__ bias, const int* __restrict__ ws,
    float* __restrict__ out, int Tmax) {
    __shared__ __align__(16) unsigned short As[1024][32];   // 64KB; reused as Ltr f32[128][68]
    __shared__ __align__(16) float biasT[16][68];

    int x = blockIdx.x;
    int xcd = x & 7;
    int rest = x >> 3;
    int lsq = rest >> 7;
    int rb = rest & 127;
    int ls = (lsq << 3) + xcd;      // pinned per XCD
    int bs = rb >> 3;
    int tq = rb & 7;

    int len = ws[bs];
    int tbase = tq << 5;
    if (tbase >= len) return;

    int tid = threadIdx.x;

    // bias -> biasT[h][beta*16+dmid]
    {
        int i0 = tid, i1 = tid + 512;
        biasT[i0 & 15][((i0 >> 8) << 4) + ((i0 & 255) >> 4)] = bias[(ls << 10) + i0];
        biasT[i1 & 15][((i1 >> 8) << 4) + ((i1 & 255) >> 4)] = bias[(ls << 10) + i1];
    }

    int lane = tid & 63;
    int wv = tid >> 6;
    int beta = wv >> 1, oh = wv & 1;
    int p = lane & 15, q = lane >> 4;

    f32x4 acc[8][2] = {};

#pragma unroll
    for (int cc = 0; cc < 6; ++cc) {
        const int kk = cc << 5;
        if constexpr (PACKED) {
            // A: 8 x global_load_lds(16B), zero VALU, LDS-linear (swizzle pre-baked)
            const char* gbase = (const char*)Wp +
                (((size_t)(ls * 6 + cc) << 12) + (wv << 6) + lane) * 16;
            char* lbase = ((char*)&As[0][0]) + ((wv << 6) << 4);
#pragma unroll
            for (int it = 0; it < 8; ++it)
                __builtin_amdgcn_global_load_lds(
                    (const __attribute__((address_space(1))) void*)(gbase + it * 8192),
                    (__attribute__((address_space(3))) void*)(lbase + it * 8192), 16, 0, 0);
        } else {
            const float* Awg = wgt + (size_t)ls * 196608;
            int arow0 = tid >> 2;
            int achk = tid & 3;
#pragma unroll
            for (int it = 0; it < 8; ++it) {
                int row = arow0 + (it << 7);
                const float* src = Awg + row * 192 + kk + (achk << 3);
                f32x4 a0 = *(const f32x4*)src;
                f32x4 a1 = *(const f32x4*)(src + 4);
                u16x8 aw = { f2bf(a0[0]), f2bf(a0[1]), f2bf(a0[2]), f2bf(a0[3]),
                             f2bf(a1[0]), f2bf(a1[1]), f2bf(a1[2]), f2bf(a1[3]) };
                *(u16x8*)&As[row][(achk ^ ((row >> 1) & 3)) << 3] = aw;
            }
        }
        // B fragments for this chunk (independent of LDS, issued before barrier)
        bf16x8 bf[2];
        if constexpr (PACKED) {
            const unsigned short* Brow = Lp + ((size_t)(bs * 256 + tbase + p)) * 768 +
                                         beta * 192 + (q << 3) + kk;
            bf[0] = ldfrag(Brow);
            bf[1] = ldfrag(Brow + 16 * 768);
        } else {
            const float* Brow = lh + (size_t)bs * 196608 + (size_t)(tbase + p) * 768 +
                                beta * 192 + (q << 3) + kk;
#pragma unroll
            for (int n = 0; n < 2; ++n) {
                const float* bp = Brow + n * 16 * 768;
                f32x4 b0 = *(const f32x4*)bp;
                f32x4 b1 = *(const f32x4*)(bp + 4);
                u16x8 bw = { f2bf(b0[0]), f2bf(b0[1]), f2bf(b0[2]), f2bf(b0[3]),
                             f2bf(b1[0]), f2bf(b1[1]), f2bf(b1[2]), f2bf(b1[3]) };
                bf[n] = __builtin_bit_cast(bf16x8, bw);
            }
        }
        __syncthreads();
        // MFMA: 8 o-subtiles x 2 t-fragments
#pragma unroll
        for (int r8 = 0; r8 < 8; ++r8) {
            int row = (beta << 8) + (oh << 7) + (r8 << 4) + p;
            bf16x8 af = ldfrag(&As[row][(q ^ ((row >> 1) & 3)) << 3]);
            acc[r8][0] = __builtin_amdgcn_mfma_f32_16x16x32_bf16(af, bf[0], acc[r8][0], 0, 0, 0);
            acc[r8][1] = __builtin_amdgcn_mfma_f32_16x16x32_bf16(af, bf[1], acc[r8][1], 0, 0, 0);
        }
        __syncthreads();
    }

    // ---- epilogue: transpose via Ltr f32[128][68], then 1KB-burst stores ----
    float* Ltr = (float*)&As[0][0];
    int cum = ws[16 + bs];
    int b = bs >> 2;
    float* batch = out + 12288;
    size_t hd0 = (size_t)((ls << 2) + b) << 4;

    int toff = lane & 3, dcq = lane >> 2;
    int col0 = (beta << 4) + (oh << 3);

#pragma unroll
    for (int r = 0; r < 4; ++r) {
#pragma unroll
        for (int n = 0; n < 2; ++n) {
            int rowL = (((n << 4) + p) << 2) + q;
            f32x4 v0 = { acc[0][n][r], acc[1][n][r], acc[2][n][r], acc[3][n][r] };
            f32x4 v1 = { acc[4][n][r], acc[5][n][r], acc[6][n][r], acc[7][n][r] };
            *(f32x4*)(Ltr + rowL * 68 + col0) = v0;
            *(f32x4*)(Ltr + rowL * 68 + col0 + 4) = v1;
        }
        __syncthreads();
#pragma unroll
        for (int gi = 0; gi < 4; ++gi) {
            int flat = (wv << 2) + gi;
            int hq = flat >> 3, t4 = flat & 7;
            int tloc = (t4 << 2) + toff;
            int h = (hq << 2) + r;
            int tglob = tbase + tloc;
            f32x4 v = *(const f32x4*)(Ltr + ((tloc << 2) + hq) * 68 + (dcq << 2));
            v += *(const f32x4*)&biasT[h][dcq << 2];
            if (tglob < len) {
                float* dst = batch + ((hd0 + h) * (size_t)Tmax + cum + tglob) * 64;
                *(f32x4*)(dst + (dcq << 2)) = v;
            }
        }
        __syncthreads();
    }
}

extern "C" void kernel_launch(void* const* d_in, const int* in_sizes, int n_in,
                              void* d_out, int out_size, void* d_ws, size_t ws_size,
                              hipStream_t stream) {
    const float* lh   = (const float*)d_in[0];
    const int*   mask = (const int*)d_in[1];
    const float* wgt  = (const float*)d_in[2];
    const float* bias = (const float*)d_in[3];
    float* out = (float*)d_out;
    int* ws = (int*)d_ws;

    int Tmax = (out_size - 12288) / 131076;

    unsigned short* Wp = (unsigned short*)((char*)d_ws + 1024);
    unsigned short* Lp = (unsigned short*)((char*)d_ws + 1024 + 12582912);
    const size_t need = 1024 + 12582912 + 6291456;
    bool packed = ws_size >= need;

    cums_kernel<<<1, 1024, 0, stream>>>(mask, ws, out + 12288 + (size_t)131072 * Tmax, Tmax);
    pooled_kernel<<<16 * 12, 256, 0, stream>>>(lh, mask, ws, out);
    zerotail_kernel<<<2048, 256, 0, stream>>>(out + 12288, ws, Tmax);

    if (packed) {
        packw_kernel<<<3072, 256, 0, stream>>>(wgt, Wp);
        packlh_kernel<<<1536, 256, 0, stream>>>(lh, Lp);
        gemm_kernel<true><<<4096, 512, 0, stream>>>(lh, wgt, Wp, Lp, bias, ws, out, Tmax);
    } else {
        gemm_kernel<false><<<4096, 512, 0, stream>>>(lh, wgt, Wp, Lp, bias, ws, out, Tmax);
    }
}